// Round 7
// baseline (2554.203 us; speedup 1.0000x reference)
//
#include <hip/hip_runtime.h>
#include <hip/hip_fp16.h>

typedef _Float16 half8 __attribute__((ext_vector_type(8)));
typedef float floatx4 __attribute__((ext_vector_type(4)));
typedef unsigned long long u64;

// workspace layout (unchanged from R4)
#define HBUF_BYTES (2ull * 16 * 1024 * 8)   // [parity][group][dim] u64 (4 f16 batches) = 256 KB
#define CTL_BYTES  (32ull * 1024)           // reserved
#define XP_OFF     (HBUF_BYTES + CTL_BYTES)
#define XP_BYTES   (512ull * 64 * 1024 * 2) // x_proj f16 [t][b][dim] = 64 MB

#define TAG_BIT    (1ull << 14)             // bit14 of h[0]: always 0 for tanh outputs

union pack4 { unsigned long long u; _Float16 h[4]; };

__device__ inline half8 cvt8(const float4 a, const float4 b) {
    half8 r;
    r[0] = (_Float16)a.x; r[1] = (_Float16)a.y; r[2] = (_Float16)a.z; r[3] = (_Float16)a.w;
    r[4] = (_Float16)b.x; r[5] = (_Float16)b.y; r[6] = (_Float16)b.z; r[7] = (_Float16)b.w;
    return r;
}

// 4 batched L1-bypass (sc0) 8B loads of a wave's slice words at byte offsets
// 0/512/1024/1536 from p. Served by the XCD's L2 (the fast sync medium).
// Single s_waitcnt at the end preserves MLP (R9 lesson: never serialize
// detection round-trips).
__device__ inline void load4_sc0(const u64* p, u64& a, u64& b, u64& c, u64& d) {
    asm volatile(
        "global_load_dwordx2 %0, %4, off sc0\n\t"
        "global_load_dwordx2 %1, %4, off offset:512 sc0\n\t"
        "global_load_dwordx2 %2, %4, off offset:1024 sc0\n\t"
        "global_load_dwordx2 %3, %4, off offset:1536 sc0\n\t"
        "s_waitcnt vmcnt(0)"
        : "=&v"(a), "=&v"(b), "=&v"(c), "=&v"(d)
        : "v"(p)
        : "memory");
}

// ---------------------------------------------------------------------------
// Phase A: x_proj = emb[src] @ W_xh^T + b_xh.
// (register-prefetch pipeline, unchanged — single-variable discipline)
// ---------------------------------------------------------------------------
__global__ __launch_bounds__(256) void xproj_kernel(
    const int* __restrict__ src, const float* __restrict__ emb,
    const float* __restrict__ Wxh, const float* __restrict__ bxh,
    _Float16* __restrict__ xp)
{
    __shared__ _Float16 As[128][40];
    __shared__ _Float16 Bs[128][40];

    const int tid  = threadIdx.x;
    const int lane = tid & 63;
    const int w    = tid >> 6;
    const int m15  = lane & 15;
    const int quad = lane >> 4;
    const int bid  = blockIdx.x;
    const int bn   = bid & 7;
    const int bm   = bid >> 3;
    const int m0   = bm * 128, n0 = bn * 128;
    const int wm   = w & 1, wn = w >> 1;

    const int  srow = tid >> 1;
    const int  scol = (tid & 1) * 16;
    const long arow = (long)src[m0 + srow] * 1024;
    const float* abase = emb + arow + scol;
    const float* bbase = Wxh + (long)(n0 + srow) * 1024 + scol;

    floatx4 zero4 = {0.f, 0.f, 0.f, 0.f};
    floatx4 acc[4][4];
#pragma unroll
    for (int mt = 0; mt < 4; mt++)
#pragma unroll
        for (int nt = 0; nt < 4; nt++) acc[mt][nt] = zero4;

    // preload k-chunk 0 into registers
    float4 a0 = *(const float4*)(abase);
    float4 a1 = *(const float4*)(abase + 4);
    float4 a2 = *(const float4*)(abase + 8);
    float4 a3 = *(const float4*)(abase + 12);
    float4 b0 = *(const float4*)(bbase);
    float4 b1 = *(const float4*)(bbase + 4);
    float4 b2 = *(const float4*)(bbase + 8);
    float4 b3 = *(const float4*)(bbase + 12);

    for (int k0 = 0; k0 < 1024; k0 += 32) {
        *(half8*)&As[srow][scol]     = cvt8(a0, a1);
        *(half8*)&As[srow][scol + 8] = cvt8(a2, a3);
        *(half8*)&Bs[srow][scol]     = cvt8(b0, b1);
        *(half8*)&Bs[srow][scol + 8] = cvt8(b2, b3);
        __syncthreads();

        if (k0 + 32 < 1024) {
            const int kn = k0 + 32;
            a0 = *(const float4*)(abase + kn);
            a1 = *(const float4*)(abase + kn + 4);
            a2 = *(const float4*)(abase + kn + 8);
            a3 = *(const float4*)(abase + kn + 12);
            b0 = *(const float4*)(bbase + kn);
            b1 = *(const float4*)(bbase + kn + 4);
            b2 = *(const float4*)(bbase + kn + 8);
            b3 = *(const float4*)(bbase + kn + 12);
        }

        half8 af[4], bf[4];
#pragma unroll
        for (int mt = 0; mt < 4; mt++)
            af[mt] = *(const half8*)&As[wm * 64 + mt * 16 + m15][quad * 8];
#pragma unroll
        for (int nt = 0; nt < 4; nt++)
            bf[nt] = *(const half8*)&Bs[wn * 64 + nt * 16 + m15][quad * 8];
#pragma unroll
        for (int mt = 0; mt < 4; mt++)
#pragma unroll
            for (int nt = 0; nt < 4; nt++)
                acc[mt][nt] = __builtin_amdgcn_mfma_f32_16x16x32_f16(
                    af[mt], bf[nt], acc[mt][nt], 0, 0, 0);

        __syncthreads();
    }

#pragma unroll
    for (int nt = 0; nt < 4; nt++) {
        const int n = n0 + wn * 64 + nt * 16 + m15;
        const float bias = bxh[n];
#pragma unroll
        for (int mt = 0; mt < 4; mt++) {
            const int mrow = m0 + wm * 64 + mt * 16 + quad * 4;
#pragma unroll
            for (int r = 0; r < 4; r++) {
                const int m = mrow + r;
                const int b = m >> 9;
                const int t = m & 511;
                xp[((long)t * 64 + b) * 1024 + n] = (_Float16)(acc[mt][nt][r] + bias);
            }
        }
    }
}

// ---------------------------------------------------------------------------
// Phase B: persistent recurrence, 256 WGs (1/CU).
// R11 = R4 structure (wave-local slice poll, cred double-buffer, ONE
// barrier/step) + DUAL-PATH SYNC on the SAME hb words:
//   R10's FETCH counter proved agent atomics are served past L2 (memory-
//   side): every poll RT ~600-900cy. With R4's indexing, members of group g
//   are WGs {g+16m}; under the %8 round-robin block->XCD mapping all of
//   them share one XCD, hence one L2. So the producer publishes each tagged
//   word TWICE: a plain global_store_dwordx2 (write-through to the shared
//   L2 -> visible to same-XCD sc0 loads in ~200cy) + the agent atomic
//   (memory-side, the R4 path). Consumers poll fast sc0 loads first; after
//   8 misses they also check the slow (atomic) words.
//   Correctness is mapping-independent: both copies carry the full tagged
//   value in one 8B-atomic word; tag-parity rejects any stale L2 content;
//   the dirty L2 line always holds the single producer's latest value, so
//   writeback can never clobber a newer memory-side copy; if producer and
//   consumer are on different XCDs the fast path simply never validates and
//   the slow path is exactly R4. No fences anywhere; numerics untouched.
// Tags/parity/back-pressure unchanged (R4 comments): tag(h_s)=((s+1)>>1)&1
// in bit14; memset zeros = valid h_0 / stale h_1; producer overwrites
// h_{t-1}'s slot only after validating all of h_t (cred barrier joins the
// 4 waves), which implies every WG finished loading h_{t-1} on both paths.
// ---------------------------------------------------------------------------
__global__ __launch_bounds__(256, 1) void rnn_kernel(
    const float* __restrict__ Whh, const _Float16* __restrict__ xp,
    unsigned long long* __restrict__ hb, float* __restrict__ out)
{
    __shared__ _Float16 hstage[16][1032];       // rows 4..15 stay zero (M-pad)
    __shared__ floatx4  cred[2][4][4][64];      // [buf][k-slice wave][ntile][lane]

    const int tid    = threadIdx.x;
    const int lane   = tid & 63;
    const int w      = tid >> 6;
    const int m15    = lane & 15;
    const int quad   = lane >> 4;
    const int wg     = blockIdx.x;
    const int g      = wg & 15;
    const int member = wg >> 4;
    const int b0     = g * 4;

    for (int i = tid; i < 16 * 1032; i += 256) ((_Float16*)hstage)[i] = (_Float16)0.f;

    // W_hh slice -> 128 VGPRs (f16), reused for all 512 steps
    half8 Wf[4][8];
#pragma unroll
    for (int nt = 0; nt < 4; nt++) {
        const float* wrow = Whh + (long)(member * 64 + nt * 16 + m15) * 1024
                                + w * 256 + quad * 8;
#pragma unroll
        for (int kk = 0; kk < 8; kk++) {
            float4 lo = *(const float4*)(wrow + kk * 32);
            float4 hi = *(const float4*)(wrow + kk * 32 + 4);
            Wf[nt][kk] = cvt8(lo, hi);
        }
    }
    __syncthreads();    // hstage zero-fill (cross-wave) visible before step 0

    const int dim = member * 64 + w * 16 + m15;
    float xv[4] = {0.f, 0.f, 0.f, 0.f};
    if (quad == 0) {
#pragma unroll
        for (int r = 0; r < 4; r++)
            xv[r] = (float)xp[((long)0 * 64 + b0 + r) * 1024 + dim];
    }

    floatx4 zero4 = {0.f, 0.f, 0.f, 0.f};

    for (int t = 0; t < 512; t++) {
        // (A) poll THIS WAVE's K-slice of h_t. Fast path: batched sc0 loads
        // from the XCD-shared L2. Slow assist after 8 misses: the R4 agent
        // atomics. Accept whichever copy validates first, per word.
        const u64* hcu = hb + (size_t)(t & 1) * 16384 + (size_t)g * 1024
                            + (size_t)w * 256;
        const u64 exp_tag = (u64)(((t + 1) >> 1) & 1) << 14;
        const u64* pl = hcu + lane;     // lane's 4 words at +0,+512,+1024,+1536 B

        u64 v[4];
        unsigned ok = 0;
        int spins = 0;
        while (ok != 15u) {
            u64 f0, f1, f2, f3;
            load4_sc0(pl, f0, f1, f2, f3);
            const u64 f[4] = {f0, f1, f2, f3};
#pragma unroll
            for (int i = 0; i < 4; i++)
                if (!(ok & (1u << i)) && ((f[i] & TAG_BIT) == exp_tag)) {
                    v[i] = f[i]; ok |= (1u << i);
                }
            if (ok == 15u) break;
            if (++spins >= 8) {
                u64 s[4];
#pragma unroll
                for (int i = 0; i < 4; i++)
                    s[i] = __hip_atomic_load(hcu + lane + 64 * i,
                                             __ATOMIC_RELAXED,
                                             __HIP_MEMORY_SCOPE_AGENT);
#pragma unroll
                for (int i = 0; i < 4; i++)
                    if (!(ok & (1u << i)) && ((s[i] & TAG_BIT) == exp_tag)) {
                        v[i] = s[i]; ok |= (1u << i);
                    }
            }
        }

        // (B) scatter into OWN columns of hstage (wave-local, no barrier)
#pragma unroll
        for (int i = 0; i < 4; i++) {
            pack4 p; p.u = v[i] & ~TAG_BIT;
            const int d = w * 256 + lane + 64 * i;
#pragma unroll
            for (int b = 0; b < 4; b++) hstage[b][d] = p.h[b];
        }

        // (C) partial GEMM over this wave's K-slice, 4 n-tiles (reads only
        // columns this wave just wrote; lgkmcnt ordering is intra-wave)
        floatx4 pacc[4];
#pragma unroll
        for (int nt = 0; nt < 4; nt++) pacc[nt] = zero4;
#pragma unroll
        for (int kk = 0; kk < 8; kk++) {
            half8 a = *(const half8*)&hstage[m15][w * 256 + kk * 32 + quad * 8];
#pragma unroll
            for (int nt = 0; nt < 4; nt++)
                pacc[nt] = __builtin_amdgcn_mfma_f32_16x16x32_f16(
                    a, Wf[nt][kk], pacc[nt], 0, 0, 0);
        }

        // (D) cross-wave K reduction, double-buffered, ONE barrier per step
        const int cb = t & 1;
#pragma unroll
        for (int nt = 0; nt < 4; nt++) cred[cb][w][nt][lane] = pacc[nt];
        __syncthreads();
        floatx4 dsum = cred[cb][0][w][lane];
#pragma unroll
        for (int ww = 1; ww < 4; ww++) dsum += cred[cb][ww][w][lane];

        // (E) epilogue: quad 0 rows 0..3 are the real batches; tanh, tag,
        // DUAL publication of the same 8B word: plain store (L2 fast path)
        // + agent atomic (memory-side slow path).
        if (quad == 0) {
            pack4 p;
#pragma unroll
            for (int r = 0; r < 4; r++) {
                float pre  = dsum[r] + xv[r];
                float e    = __expf(2.0f * pre);
                float hval = 1.0f - 2.0f / (e + 1.0f);   // tanh
                p.h[r] = (_Float16)hval;
                if (t == 511) out[(b0 + r) * 1024 + dim] = hval;
            }
            if (t < 511) {
                unsigned long long* hnu =
                    hb + (size_t)((t + 1) & 1) * 16384 + (size_t)g * 1024;
                const u64 st_tag = (u64)(((t + 2) >> 1) & 1) << 14;
                const u64 word = p.u | st_tag;
                u64* dst = hnu + dim;
                asm volatile("global_store_dwordx2 %0, %1, off"
                             :: "v"(dst), "v"(word) : "memory");
                __hip_atomic_store(dst, word, __ATOMIC_RELAXED,
                                   __HIP_MEMORY_SCOPE_AGENT);
            }
        }

        // (F) x_proj prefetch for t+1; drains while the next poll spins
        if (t < 511 && quad == 0) {
#pragma unroll
            for (int r = 0; r < 4; r++)
                xv[r] = (float)xp[((long)(t + 1) * 64 + b0 + r) * 1024 + dim];
        }
    }
}

extern "C" void kernel_launch(void* const* d_in, const int* in_sizes, int n_in,
                              void* d_out, int out_size, void* d_ws, size_t ws_size,
                              hipStream_t stream) {
    const int*   src = (const int*)d_in[0];
    const float* emb = (const float*)d_in[1];
    const float* Wxh = (const float*)d_in[2];
    const float* bxh = (const float*)d_in[3];
    const float* Whh = (const float*)d_in[4];
    float* out = (float*)d_out;

    char* ws = (char*)d_ws;
    unsigned long long* hb = (unsigned long long*)ws;
    _Float16* xp = (_Float16*)(ws + XP_OFF);

    // zero h buffers: parity-0 zeros ARE h_0 (tag 0 = expected); parity-1
    // zeros are stale for h_1, so consumers block until real h_1 arrives.
    hipMemsetAsync(ws, 0, HBUF_BYTES, stream);

    hipLaunchKernelGGL(xproj_kernel, dim3(2048), dim3(256), 0, stream,
                       src, emb, Wxh, bxh, xp);

    hipLaunchKernelGGL(rnn_kernel, dim3(256), dim3(256), 0, stream,
                       Whh, xp, hb, out);
}

// Round 8
// 1188.552 us; speedup vs baseline: 2.1490x; 2.1490x over previous
//
#include <hip/hip_runtime.h>
#include <hip/hip_fp16.h>

typedef _Float16 half8 __attribute__((ext_vector_type(8)));
typedef float floatx4 __attribute__((ext_vector_type(4)));
typedef unsigned long long u64;

// workspace layout
#define HBUF_BYTES (2ull * 16 * 1024 * 8)   // [parity][group][dim] u64 (4 f16 batches) = 256 KB
#define CTL_BYTES  (32ull * 1024)           // reserved
#define XP_OFF     (HBUF_BYTES + CTL_BYTES)
#define XP_BYTES   (512ull * 64 * 1024 * 2) // x_proj f16 [t][b][dim] = 64 MB

#define TAG_BIT    (1ull << 14)             // bit14 of h[0]: always 0 for tanh outputs

union pack4 { unsigned long long u; _Float16 h[4]; };

__device__ inline half8 cvt8(const float4 a, const float4 b) {
    half8 r;
    r[0] = (_Float16)a.x; r[1] = (_Float16)a.y; r[2] = (_Float16)a.z; r[3] = (_Float16)a.w;
    r[4] = (_Float16)b.x; r[5] = (_Float16)b.y; r[6] = (_Float16)b.z; r[7] = (_Float16)b.w;
    return r;
}

// ---------------------------------------------------------------------------
// Phase A: x_proj = emb[src] @ W_xh^T + b_xh.
// R12: double-buffered LDS, ONE barrier per K-step (was 2). Per iteration:
//   issue chunk k+1 global loads (drain under MFMAs) -> fragment ds_reads +
//   16 MFMAs/wave from buf[cur] -> cvt + ds_write chunk k+1 into buf[cur^1]
//   -> barrier. RAW: writes(buf^1)@k -> barrier -> reads(buf^1)@k+1.
//   WAR: reads(buf)@k -> barrier -> writes(buf)@k+1.
// ---------------------------------------------------------------------------
__global__ __launch_bounds__(256) void xproj_kernel(
    const int* __restrict__ src, const float* __restrict__ emb,
    const float* __restrict__ Wxh, const float* __restrict__ bxh,
    _Float16* __restrict__ xp)
{
    __shared__ _Float16 As[2][128][40];
    __shared__ _Float16 Bs[2][128][40];

    const int tid  = threadIdx.x;
    const int lane = tid & 63;
    const int w    = tid >> 6;
    const int m15  = lane & 15;
    const int quad = lane >> 4;
    const int bid  = blockIdx.x;
    const int bn   = bid & 7;
    const int bm   = bid >> 3;
    const int m0   = bm * 128, n0 = bn * 128;
    const int wm   = w & 1, wn = w >> 1;

    const int  srow = tid >> 1;
    const int  scol = (tid & 1) * 16;
    const long arow = (long)src[m0 + srow] * 1024;
    const float* abase = emb + arow + scol;
    const float* bbase = Wxh + (long)(n0 + srow) * 1024 + scol;

    floatx4 zero4 = {0.f, 0.f, 0.f, 0.f};
    floatx4 acc[4][4];
#pragma unroll
    for (int mt = 0; mt < 4; mt++)
#pragma unroll
        for (int nt = 0; nt < 4; nt++) acc[mt][nt] = zero4;

    // prologue: load + stage chunk 0 into buf 0
    {
        float4 a0 = *(const float4*)(abase);
        float4 a1 = *(const float4*)(abase + 4);
        float4 a2 = *(const float4*)(abase + 8);
        float4 a3 = *(const float4*)(abase + 12);
        float4 b0 = *(const float4*)(bbase);
        float4 b1 = *(const float4*)(bbase + 4);
        float4 b2 = *(const float4*)(bbase + 8);
        float4 b3 = *(const float4*)(bbase + 12);
        *(half8*)&As[0][srow][scol]     = cvt8(a0, a1);
        *(half8*)&As[0][srow][scol + 8] = cvt8(a2, a3);
        *(half8*)&Bs[0][srow][scol]     = cvt8(b0, b1);
        *(half8*)&Bs[0][srow][scol + 8] = cvt8(b2, b3);
    }
    __syncthreads();

    for (int kidx = 0; kidx < 32; kidx++) {
        const int cur = kidx & 1;

        // (1) issue chunk k+1 global loads; they drain under the MFMA phase
        float4 a0, a1, a2, a3, b0, b1, b2, b3;
        if (kidx + 1 < 32) {
            const int kn = (kidx + 1) * 32;
            a0 = *(const float4*)(abase + kn);
            a1 = *(const float4*)(abase + kn + 4);
            a2 = *(const float4*)(abase + kn + 8);
            a3 = *(const float4*)(abase + kn + 12);
            b0 = *(const float4*)(bbase + kn);
            b1 = *(const float4*)(bbase + kn + 4);
            b2 = *(const float4*)(bbase + kn + 8);
            b3 = *(const float4*)(bbase + kn + 12);
        }

        // (2) fragments + MFMAs from buf[cur]
        half8 af[4], bf[4];
#pragma unroll
        for (int mt = 0; mt < 4; mt++)
            af[mt] = *(const half8*)&As[cur][wm * 64 + mt * 16 + m15][quad * 8];
#pragma unroll
        for (int nt = 0; nt < 4; nt++)
            bf[nt] = *(const half8*)&Bs[cur][wn * 64 + nt * 16 + m15][quad * 8];
#pragma unroll
        for (int mt = 0; mt < 4; mt++)
#pragma unroll
            for (int nt = 0; nt < 4; nt++)
                acc[mt][nt] = __builtin_amdgcn_mfma_f32_16x16x32_f16(
                    af[mt], bf[nt], acc[mt][nt], 0, 0, 0);

        // (3) stage chunk k+1 into the alternate buffer
        if (kidx + 1 < 32) {
            *(half8*)&As[cur ^ 1][srow][scol]     = cvt8(a0, a1);
            *(half8*)&As[cur ^ 1][srow][scol + 8] = cvt8(a2, a3);
            *(half8*)&Bs[cur ^ 1][srow][scol]     = cvt8(b0, b1);
            *(half8*)&Bs[cur ^ 1][srow][scol + 8] = cvt8(b2, b3);
        }

        // (4) the single barrier per K-step
        __syncthreads();
    }

#pragma unroll
    for (int nt = 0; nt < 4; nt++) {
        const int n = n0 + wn * 64 + nt * 16 + m15;
        const float bias = bxh[n];
#pragma unroll
        for (int mt = 0; mt < 4; mt++) {
            const int mrow = m0 + wm * 64 + mt * 16 + quad * 4;
#pragma unroll
            for (int r = 0; r < 4; r++) {
                const int m = mrow + r;
                const int b = m >> 9;
                const int t = m & 511;
                xp[((long)t * 64 + b) * 1024 + n] = (_Float16)(acc[mt][nt][r] + bias);
            }
        }
    }
}

// ---------------------------------------------------------------------------
// Phase B: persistent recurrence, 256 WGs (1/CU).
// R12 = EXACT REVERT to the R8 kernel (best measured: 850 us). R9/R10/R11
// falsified every deviation from this sync shape:
//   - per-chunk serial polling: +460us (serialized detection RTs)
//   - full-h polling per wave: +780us (4x memory-side poll traffic; FETCH
//     proved agent atomics are served past L2)
//   - dual plain+atomic publication: +1400us (same-line writeback ping-pong,
//     WRITE_SIZE doubled)
// Structure: R5 comm layout (packed [parity][group][dim] u64, one 8B store
// per producer lane, coalesced poll) + WAVE-LOCAL staging (wave w polls its
// own K-slice [256w,256w+256), writes only hstage columns it alone reads ->
// no staging barrier) + double-buffered cred -> ONE barrier per step.
// Tags: tag(h_s) = ((s+1)>>1)&1 in bit14 of h[0]; memset zeros = valid h_0
// (parity 0), stale for h_1 (parity 1). Back-pressure: producer stores
// h_{t+1} only after validating h_t, which implies every member finished
// polling h_{t-1} (the slot being overwritten). No fences anywhere.
// ---------------------------------------------------------------------------
__global__ __launch_bounds__(256, 1) void rnn_kernel(
    const float* __restrict__ Whh, const _Float16* __restrict__ xp,
    unsigned long long* __restrict__ hb, float* __restrict__ out)
{
    __shared__ _Float16 hstage[16][1032];       // rows 4..15 stay zero (M-pad)
    __shared__ floatx4  cred[2][4][4][64];      // [buf][k-slice wave][ntile][lane]

    const int tid    = threadIdx.x;
    const int lane   = tid & 63;
    const int w      = tid >> 6;
    const int m15    = lane & 15;
    const int quad   = lane >> 4;
    const int wg     = blockIdx.x;
    const int g      = wg & 15;
    const int member = wg >> 4;
    const int b0     = g * 4;

    for (int i = tid; i < 16 * 1032; i += 256) ((_Float16*)hstage)[i] = (_Float16)0.f;

    // W_hh slice -> 128 VGPRs (f16), reused for all 512 steps
    half8 Wf[4][8];
#pragma unroll
    for (int nt = 0; nt < 4; nt++) {
        const float* wrow = Whh + (long)(member * 64 + nt * 16 + m15) * 1024
                                + w * 256 + quad * 8;
#pragma unroll
        for (int kk = 0; kk < 8; kk++) {
            float4 lo = *(const float4*)(wrow + kk * 32);
            float4 hi = *(const float4*)(wrow + kk * 32 + 4);
            Wf[nt][kk] = cvt8(lo, hi);
        }
    }
    __syncthreads();    // hstage zero-fill (cross-wave) visible before step 0

    const int dim = member * 64 + w * 16 + m15;
    float xv[4] = {0.f, 0.f, 0.f, 0.f};
    if (quad == 0) {
#pragma unroll
        for (int r = 0; r < 4; r++)
            xv[r] = (float)xp[((long)0 * 64 + b0 + r) * 1024 + dim];
    }

    floatx4 zero4 = {0.f, 0.f, 0.f, 0.f};

    for (int t = 0; t < 512; t++) {
        // (A) poll THIS WAVE's K-slice of h_t (coalesced: 64 consecutive
        // u64 per load instruction), tags in the data words themselves.
        const u64* hcu = hb + (size_t)(t & 1) * 16384 + (size_t)g * 1024
                            + (size_t)w * 256;
        const u64 exp_tag = (u64)(((t + 1) >> 1) & 1) << 14;

        u64 v[4];
        for (;;) {
            bool ok = true;
#pragma unroll
            for (int i = 0; i < 4; i++)
                v[i] = __hip_atomic_load(hcu + lane + 64 * i, __ATOMIC_RELAXED,
                                         __HIP_MEMORY_SCOPE_AGENT);
#pragma unroll
            for (int i = 0; i < 4; i++)
                ok &= ((v[i] & TAG_BIT) == exp_tag);
            if (ok) break;
        }

        // (B) scatter into OWN columns of hstage (wave-local, no barrier)
#pragma unroll
        for (int i = 0; i < 4; i++) {
            pack4 p; p.u = v[i] & ~TAG_BIT;
            const int d = w * 256 + lane + 64 * i;
#pragma unroll
            for (int b = 0; b < 4; b++) hstage[b][d] = p.h[b];
        }

        // (C) partial GEMM over this wave's K-slice, 4 n-tiles (reads only
        // columns this wave just wrote; lgkmcnt ordering is intra-wave)
        floatx4 pacc[4];
#pragma unroll
        for (int nt = 0; nt < 4; nt++) pacc[nt] = zero4;
#pragma unroll
        for (int kk = 0; kk < 8; kk++) {
            half8 a = *(const half8*)&hstage[m15][w * 256 + kk * 32 + quad * 8];
#pragma unroll
            for (int nt = 0; nt < 4; nt++)
                pacc[nt] = __builtin_amdgcn_mfma_f32_16x16x32_f16(
                    a, Wf[nt][kk], pacc[nt], 0, 0, 0);
        }

        // (D) cross-wave K reduction, double-buffered, ONE barrier per step
        const int cb = t & 1;
#pragma unroll
        for (int nt = 0; nt < 4; nt++) cred[cb][w][nt][lane] = pacc[nt];
        __syncthreads();
        floatx4 dsum = cred[cb][0][w][lane];
#pragma unroll
        for (int ww = 1; ww < 4; ww++) dsum += cred[cb][ww][w][lane];

        // (E) epilogue: quad 0 rows 0..3 are the real batches; tanh, tag,
        // one 8B relaxed agent-atomic store. The store IS the publication.
        if (quad == 0) {
            pack4 p;
#pragma unroll
            for (int r = 0; r < 4; r++) {
                float pre  = dsum[r] + xv[r];
                float e    = __expf(2.0f * pre);
                float hval = 1.0f - 2.0f / (e + 1.0f);   // tanh
                p.h[r] = (_Float16)hval;
                if (t == 511) out[(b0 + r) * 1024 + dim] = hval;
            }
            if (t < 511) {
                unsigned long long* hnu =
                    hb + (size_t)((t + 1) & 1) * 16384 + (size_t)g * 1024;
                const u64 st_tag = (u64)(((t + 2) >> 1) & 1) << 14;
                __hip_atomic_store(hnu + dim, p.u | st_tag, __ATOMIC_RELAXED,
                                   __HIP_MEMORY_SCOPE_AGENT);
            }
        }

        // (F) x_proj prefetch for t+1; drains while the next poll spins
        if (t < 511 && quad == 0) {
#pragma unroll
            for (int r = 0; r < 4; r++)
                xv[r] = (float)xp[((long)(t + 1) * 64 + b0 + r) * 1024 + dim];
        }
    }
}

extern "C" void kernel_launch(void* const* d_in, const int* in_sizes, int n_in,
                              void* d_out, int out_size, void* d_ws, size_t ws_size,
                              hipStream_t stream) {
    const int*   src = (const int*)d_in[0];
    const float* emb = (const float*)d_in[1];
    const float* Wxh = (const float*)d_in[2];
    const float* bxh = (const float*)d_in[3];
    const float* Whh = (const float*)d_in[4];
    float* out = (float*)d_out;

    char* ws = (char*)d_ws;
    unsigned long long* hb = (unsigned long long*)ws;
    _Float16* xp = (_Float16*)(ws + XP_OFF);

    // zero h buffers: parity-0 zeros ARE h_0 (tag 0 = expected); parity-1
    // zeros are stale for h_1, so consumers block until real h_1 arrives.
    hipMemsetAsync(ws, 0, HBUF_BYTES, stream);

    hipLaunchKernelGGL(xproj_kernel, dim3(2048), dim3(256), 0, stream,
                       src, emb, Wxh, bxh, xp);

    hipLaunchKernelGGL(rnn_kernel, dim3(256), dim3(256), 0, stream,
                       Whh, xp, hb, out);
}

// Round 9
// 1164.847 us; speedup vs baseline: 2.1927x; 1.0204x over previous
//
#include <hip/hip_runtime.h>
#include <hip/hip_fp16.h>

typedef _Float16 half8 __attribute__((ext_vector_type(8)));
typedef float floatx4 __attribute__((ext_vector_type(4)));
typedef unsigned long long u64;

// workspace layout
#define HBUF_BYTES (2ull * 16 * 1024 * 8)   // [parity][group][dim] u64 (4 f16 batches) = 256 KB
#define CTL_BYTES  (32ull * 1024)           // reserved
#define XP_OFF     (HBUF_BYTES + CTL_BYTES)
#define XP_BYTES   (512ull * 64 * 1024 * 2) // x_proj f16 [t][b][dim] = 64 MB

#define TAG_BIT    (1ull << 14)             // bit14 of h[0]: always 0 for tanh outputs

union pack4 { unsigned long long u; _Float16 h[4]; };

__device__ inline half8 cvt8(const float4 a, const float4 b) {
    half8 r;
    r[0] = (_Float16)a.x; r[1] = (_Float16)a.y; r[2] = (_Float16)a.z; r[3] = (_Float16)a.w;
    r[4] = (_Float16)b.x; r[5] = (_Float16)b.y; r[6] = (_Float16)b.z; r[7] = (_Float16)b.w;
    return r;
}

// ---------------------------------------------------------------------------
// Phase A: x_proj = emb[src] @ W_xh^T + b_xh.
// R13: XCD-AFFINITY BLOCK REMAP. Traffic math (R12 post-mortem): per K-step
// each block loads 32KB of f32 tiles -> 2048x32x32KB = 2.1GB, ~330us at HBM
// BW — xproj is tile-traffic-bound. The 8 blocks sharing one A-tile (same
// bm) were landing on 8 different XCDs (round-robin bid%8), each refetching
// the same 512KB; W_xh (4MB = one XCD L2) was streamed by all XCDs' CUs.
// Remap so all 8 bn-siblings of a bm-group sit on ONE XCD, adjacent in
// dispatch: xcd=bid&7, slot=bid>>3, bm=(slot>>3)*8+xcd, bn=slot&7
// (bijective: XCD x owns bm === x mod 8). A-tiles then hit L2 8x; each
// XCD's 8 disjoint 512KB W row-slices stay L2-resident for its 256 blocks.
// Expected HBM: ~A-once(131MB) + W x8(32MB) + xp writes(64MB) ~ 230MB.
// Body: single-buffer register-prefetch pipeline (R8 form, 41KB LDS ->
// 3 blocks/CU for latency hiding once L2-bound).
// ---------------------------------------------------------------------------
__global__ __launch_bounds__(256) void xproj_kernel(
    const int* __restrict__ src, const float* __restrict__ emb,
    const float* __restrict__ Wxh, const float* __restrict__ bxh,
    _Float16* __restrict__ xp)
{
    __shared__ _Float16 As[128][40];
    __shared__ _Float16 Bs[128][40];

    const int tid  = threadIdx.x;
    const int lane = tid & 63;
    const int w    = tid >> 6;
    const int m15  = lane & 15;
    const int quad = lane >> 4;
    const int bid  = blockIdx.x;
    const int xcd  = bid & 7;
    const int slot = bid >> 3;
    const int bm   = (slot >> 3) * 8 + xcd;   // all 8 bn of this bm on one XCD
    const int bn   = slot & 7;
    const int m0   = bm * 128, n0 = bn * 128;
    const int wm   = w & 1, wn = w >> 1;

    const int  srow = tid >> 1;
    const int  scol = (tid & 1) * 16;
    const long arow = (long)src[m0 + srow] * 1024;
    const float* abase = emb + arow + scol;
    const float* bbase = Wxh + (long)(n0 + srow) * 1024 + scol;

    floatx4 zero4 = {0.f, 0.f, 0.f, 0.f};
    floatx4 acc[4][4];
#pragma unroll
    for (int mt = 0; mt < 4; mt++)
#pragma unroll
        for (int nt = 0; nt < 4; nt++) acc[mt][nt] = zero4;

    // preload k-chunk 0 into registers
    float4 a0 = *(const float4*)(abase);
    float4 a1 = *(const float4*)(abase + 4);
    float4 a2 = *(const float4*)(abase + 8);
    float4 a3 = *(const float4*)(abase + 12);
    float4 b0 = *(const float4*)(bbase);
    float4 b1 = *(const float4*)(bbase + 4);
    float4 b2 = *(const float4*)(bbase + 8);
    float4 b3 = *(const float4*)(bbase + 12);

    for (int k0 = 0; k0 < 1024; k0 += 32) {
        *(half8*)&As[srow][scol]     = cvt8(a0, a1);
        *(half8*)&As[srow][scol + 8] = cvt8(a2, a3);
        *(half8*)&Bs[srow][scol]     = cvt8(b0, b1);
        *(half8*)&Bs[srow][scol + 8] = cvt8(b2, b3);
        __syncthreads();

        if (k0 + 32 < 1024) {
            const int kn = k0 + 32;
            a0 = *(const float4*)(abase + kn);
            a1 = *(const float4*)(abase + kn + 4);
            a2 = *(const float4*)(abase + kn + 8);
            a3 = *(const float4*)(abase + kn + 12);
            b0 = *(const float4*)(bbase + kn);
            b1 = *(const float4*)(bbase + kn + 4);
            b2 = *(const float4*)(bbase + kn + 8);
            b3 = *(const float4*)(bbase + kn + 12);
        }

        half8 af[4], bf[4];
#pragma unroll
        for (int mt = 0; mt < 4; mt++)
            af[mt] = *(const half8*)&As[wm * 64 + mt * 16 + m15][quad * 8];
#pragma unroll
        for (int nt = 0; nt < 4; nt++)
            bf[nt] = *(const half8*)&Bs[wn * 64 + nt * 16 + m15][quad * 8];
#pragma unroll
        for (int mt = 0; mt < 4; mt++)
#pragma unroll
            for (int nt = 0; nt < 4; nt++)
                acc[mt][nt] = __builtin_amdgcn_mfma_f32_16x16x32_f16(
                    af[mt], bf[nt], acc[mt][nt], 0, 0, 0);

        __syncthreads();
    }

#pragma unroll
    for (int nt = 0; nt < 4; nt++) {
        const int n = n0 + wn * 64 + nt * 16 + m15;
        const float bias = bxh[n];
#pragma unroll
        for (int mt = 0; mt < 4; mt++) {
            const int mrow = m0 + wm * 64 + mt * 16 + quad * 4;
#pragma unroll
            for (int r = 0; r < 4; r++) {
                const int m = mrow + r;
                const int b = m >> 9;
                const int t = m & 511;
                xp[((long)t * 64 + b) * 1024 + n] = (_Float16)(acc[mt][nt][r] + bias);
            }
        }
    }
}

// ---------------------------------------------------------------------------
// Phase B: persistent recurrence, 256 WGs (1/CU).
// UNCHANGED from R12 (= R8, best measured 850-854us). R9/R10/R11 falsified
// every deviation from this sync shape (serial per-chunk polls, full-h
// polls, dual plain+atomic publication). Do not touch.
// Structure: packed [parity][group][dim] u64 comm words + wave-local
// staging (wave w polls its own K-slice, writes only hstage columns it
// alone reads -> no staging barrier) + double-buffered cred -> ONE barrier
// per step. Tags: tag(h_s) = ((s+1)>>1)&1 in bit14 of h[0]; memset zeros =
// valid h_0 (parity 0), stale for h_1 (parity 1). Back-pressure: producer
// stores h_{t+1} only after validating h_t, which implies every member
// finished polling h_{t-1} (the slot being overwritten). No fences.
// ---------------------------------------------------------------------------
__global__ __launch_bounds__(256, 1) void rnn_kernel(
    const float* __restrict__ Whh, const _Float16* __restrict__ xp,
    unsigned long long* __restrict__ hb, float* __restrict__ out)
{
    __shared__ _Float16 hstage[16][1032];       // rows 4..15 stay zero (M-pad)
    __shared__ floatx4  cred[2][4][4][64];      // [buf][k-slice wave][ntile][lane]

    const int tid    = threadIdx.x;
    const int lane   = tid & 63;
    const int w      = tid >> 6;
    const int m15    = lane & 15;
    const int quad   = lane >> 4;
    const int wg     = blockIdx.x;
    const int g      = wg & 15;
    const int member = wg >> 4;
    const int b0     = g * 4;

    for (int i = tid; i < 16 * 1032; i += 256) ((_Float16*)hstage)[i] = (_Float16)0.f;

    // W_hh slice -> 128 VGPRs (f16), reused for all 512 steps
    half8 Wf[4][8];
#pragma unroll
    for (int nt = 0; nt < 4; nt++) {
        const float* wrow = Whh + (long)(member * 64 + nt * 16 + m15) * 1024
                                + w * 256 + quad * 8;
#pragma unroll
        for (int kk = 0; kk < 8; kk++) {
            float4 lo = *(const float4*)(wrow + kk * 32);
            float4 hi = *(const float4*)(wrow + kk * 32 + 4);
            Wf[nt][kk] = cvt8(lo, hi);
        }
    }
    __syncthreads();    // hstage zero-fill (cross-wave) visible before step 0

    const int dim = member * 64 + w * 16 + m15;
    float xv[4] = {0.f, 0.f, 0.f, 0.f};
    if (quad == 0) {
#pragma unroll
        for (int r = 0; r < 4; r++)
            xv[r] = (float)xp[((long)0 * 64 + b0 + r) * 1024 + dim];
    }

    floatx4 zero4 = {0.f, 0.f, 0.f, 0.f};

    for (int t = 0; t < 512; t++) {
        // (A) poll THIS WAVE's K-slice of h_t (coalesced: 64 consecutive
        // u64 per load instruction), tags in the data words themselves.
        const u64* hcu = hb + (size_t)(t & 1) * 16384 + (size_t)g * 1024
                            + (size_t)w * 256;
        const u64 exp_tag = (u64)(((t + 1) >> 1) & 1) << 14;

        u64 v[4];
        for (;;) {
            bool ok = true;
#pragma unroll
            for (int i = 0; i < 4; i++)
                v[i] = __hip_atomic_load(hcu + lane + 64 * i, __ATOMIC_RELAXED,
                                         __HIP_MEMORY_SCOPE_AGENT);
#pragma unroll
            for (int i = 0; i < 4; i++)
                ok &= ((v[i] & TAG_BIT) == exp_tag);
            if (ok) break;
        }

        // (B) scatter into OWN columns of hstage (wave-local, no barrier)
#pragma unroll
        for (int i = 0; i < 4; i++) {
            pack4 p; p.u = v[i] & ~TAG_BIT;
            const int d = w * 256 + lane + 64 * i;
#pragma unroll
            for (int b = 0; b < 4; b++) hstage[b][d] = p.h[b];
        }

        // (C) partial GEMM over this wave's K-slice, 4 n-tiles (reads only
        // columns this wave just wrote; lgkmcnt ordering is intra-wave)
        floatx4 pacc[4];
#pragma unroll
        for (int nt = 0; nt < 4; nt++) pacc[nt] = zero4;
#pragma unroll
        for (int kk = 0; kk < 8; kk++) {
            half8 a = *(const half8*)&hstage[m15][w * 256 + kk * 32 + quad * 8];
#pragma unroll
            for (int nt = 0; nt < 4; nt++)
                pacc[nt] = __builtin_amdgcn_mfma_f32_16x16x32_f16(
                    a, Wf[nt][kk], pacc[nt], 0, 0, 0);
        }

        // (D) cross-wave K reduction, double-buffered, ONE barrier per step
        const int cb = t & 1;
#pragma unroll
        for (int nt = 0; nt < 4; nt++) cred[cb][w][nt][lane] = pacc[nt];
        __syncthreads();
        floatx4 dsum = cred[cb][0][w][lane];
#pragma unroll
        for (int ww = 1; ww < 4; ww++) dsum += cred[cb][ww][w][lane];

        // (E) epilogue: quad 0 rows 0..3 are the real batches; tanh, tag,
        // one 8B relaxed agent-atomic store. The store IS the publication.
        if (quad == 0) {
            pack4 p;
#pragma unroll
            for (int r = 0; r < 4; r++) {
                float pre  = dsum[r] + xv[r];
                float e    = __expf(2.0f * pre);
                float hval = 1.0f - 2.0f / (e + 1.0f);   // tanh
                p.h[r] = (_Float16)hval;
                if (t == 511) out[(b0 + r) * 1024 + dim] = hval;
            }
            if (t < 511) {
                unsigned long long* hnu =
                    hb + (size_t)((t + 1) & 1) * 16384 + (size_t)g * 1024;
                const u64 st_tag = (u64)(((t + 2) >> 1) & 1) << 14;
                __hip_atomic_store(hnu + dim, p.u | st_tag, __ATOMIC_RELAXED,
                                   __HIP_MEMORY_SCOPE_AGENT);
            }
        }

        // (F) x_proj prefetch for t+1; drains while the next poll spins
        if (t < 511 && quad == 0) {
#pragma unroll
            for (int r = 0; r < 4; r++)
                xv[r] = (float)xp[((long)(t + 1) * 64 + b0 + r) * 1024 + dim];
        }
    }
}

extern "C" void kernel_launch(void* const* d_in, const int* in_sizes, int n_in,
                              void* d_out, int out_size, void* d_ws, size_t ws_size,
                              hipStream_t stream) {
    const int*   src = (const int*)d_in[0];
    const float* emb = (const float*)d_in[1];
    const float* Wxh = (const float*)d_in[2];
    const float* bxh = (const float*)d_in[3];
    const float* Whh = (const float*)d_in[4];
    float* out = (float*)d_out;

    char* ws = (char*)d_ws;
    unsigned long long* hb = (unsigned long long*)ws;
    _Float16* xp = (_Float16*)(ws + XP_OFF);

    // zero h buffers: parity-0 zeros ARE h_0 (tag 0 = expected); parity-1
    // zeros are stale for h_1, so consumers block until real h_1 arrives.
    hipMemsetAsync(ws, 0, HBUF_BYTES, stream);

    hipLaunchKernelGGL(xproj_kernel, dim3(2048), dim3(256), 0, stream,
                       src, emb, Wxh, bxh, xp);

    hipLaunchKernelGGL(rnn_kernel, dim3(256), dim3(256), 0, stream,
                       Whh, xp, hb, out);
}